// Round 4
// baseline (175.007 us; speedup 1.0000x reference)
//
#include <hip/hip_runtime.h>

// Problem constants (fixed by setup_inputs): B=32, C=64, H=W=32, N=16 branches.
#define CH      64
#define BATCH   32
#define NBR     16
#define HW4     256           // float4 per channel plane (H*W = 1024 floats)

typedef float v4f __attribute__((ext_vector_type(4)));

// ---------------------------------------------------------------------------
// Kernel A: per-(batch, channel) sum / sumsq. Unchanged (≈3-4 µs).
// grid = 512: b = bid & 31, cg = bid >> 5. One wave reduces one channel plane
// (1024 floats, coalesced float4), one deterministic partial slot, no atomics.
// ---------------------------------------------------------------------------
__global__ void __launch_bounds__(256) bn_partial(const float* __restrict__ x,
                                                  float* __restrict__ partials) {
    const int b    = blockIdx.x & 31;
    const int cg   = blockIdx.x >> 5;     // 0..15
    const int wave = threadIdx.x >> 6;    // 0..3
    const int lane = threadIdx.x & 63;
    const int c    = cg * 4 + wave;

    const v4f* xp = (const v4f*)x + (b * CH + c) * HW4;
    float s = 0.f, sq = 0.f;
#pragma unroll
    for (int i = 0; i < 4; ++i) {
        const v4f v = xp[i * 64 + lane];
        s  += v.x + v.y + v.z + v.w;
        sq += v.x * v.x + v.y * v.y + v.z * v.z + v.w * v.w;
    }
#pragma unroll
    for (int off = 32; off > 0; off >>= 1) {
        s  += __shfl_down(s, off);
        sq += __shfl_down(sq, off);
    }
    if (lane == 0) {
        partials[(b * CH + c) * 2 + 0] = s;
        partials[(b * CH + c) * 2 + 1] = sq;
    }
}

// ---------------------------------------------------------------------------
// Kernel B: fused finalize + apply — MLP-maximized issue structure.
//
// ROUND-4 CHANGE (single variable): per-thread ILP + grid TLP.
// Previous versions: serial load->fma->store chain (1 load in flight),
// 1024 blocks. All write-pattern variants timed identical => latency/ILP
// suspected, not traffic. Now: each thread owns 8 CONSECUTIVE out-float4
// (128 B/lane, 8 KB/wave contiguous), issues all 8 x-loads back-to-back
// (8 outstanding VMEM reads), then 8 fma+stores back-to-back — the closest
// a read+write kernel gets to the 6.5 TB/s fill kernel's issue pattern.
// grid = 4096 blocks (16/CU queued) for full occupancy.
//
// out f4 index = b*2^18 + n*2^14 + c*2^8 + hw4. Block covers 2048 f4
// (= 8 channel planes of one (b,n)); thread t covers [t*8, t*8+8) within it,
// which stays inside ONE channel plane (256 f4/plane, 8 | 256).
// Preamble: threads 0..7 fold the 32 per-batch partials for the block's 8
// channels into scale/shift in LDS (finalize kernel stays fused).
// ---------------------------------------------------------------------------
__global__ void __launch_bounds__(256) bn_apply(const float* __restrict__ x,
                                                const float* __restrict__ partials,
                                                const float* __restrict__ gamma,
                                                const float* __restrict__ beta,
                                                float* __restrict__ out) {
    const int t     = threadIdx.x;          // 0..255
    const int bbase = blockIdx.x << 11;     // block's first out-f4 (2048 per block)
    const int b     = bbase >> 18;
    const int n     = (bbase >> 14) & 15;
    const int c0    = (bbase >> 8) & 63;    // multiple of 8

    __shared__ float sa[8], ss[8];
    if (t < 8) {
        const int c = c0 + t;
        float S = 0.f, Q = 0.f;
#pragma unroll
        for (int bb = 0; bb < 32; ++bb) {
            S += partials[(bb * CH + c) * 2 + 0];
            Q += partials[(bb * CH + c) * 2 + 1];
        }
        const float mean = S * (1.0f / 32768.0f);
        const float var  = Q * (1.0f / 32768.0f) - mean * mean;
        const float inv  = rsqrtf(var + 1e-5f);
        const float a    = gamma[n * CH + c] * inv;
        sa[t] = a;
        ss[t] = beta[n * CH + c] - a * mean;
    }
    __syncthreads();

    const int lc  = (t * 8) >> 8;           // local channel 0..7 (thread-uniform)
    const int hw4 = (t * 8) & 255;          // 0,8,...,248
    const float a = sa[lc];
    const float s = ss[lc];

    const v4f* xp = (const v4f*)x + (b * CH + c0 + lc) * HW4 + hw4;
    v4f*       op = (v4f*)out + bbase + t * 8;

    // 8 loads in flight, then 8 fma+stores — no dependent read between stores.
    v4f v[8];
#pragma unroll
    for (int k = 0; k < 8; ++k) v[k] = xp[k];
#pragma unroll
    for (int k = 0; k < 8; ++k) {
        v4f o;
        o.x = fmaf(a, v[k].x, s);
        o.y = fmaf(a, v[k].y, s);
        o.z = fmaf(a, v[k].z, s);
        o.w = fmaf(a, v[k].w, s);
        op[k] = o;
    }
}

extern "C" void kernel_launch(void* const* d_in, const int* in_sizes, int n_in,
                              void* d_out, int out_size, void* d_ws, size_t ws_size,
                              hipStream_t stream) {
    const float* x     = (const float*)d_in[0];   // [32,64,32,32]
    const float* gamma = (const float*)d_in[1];   // [16,64]
    const float* beta  = (const float*)d_in[2];   // [16,64]
    float* out = (float*)d_out;                   // [32,1024,32,32]
    float* ws  = (float*)d_ws;

    float* partials = ws;   // 32*64*2 = 4096 floats, deterministic slots

    bn_partial<<<512, 256, 0, stream>>>(x, partials);
    bn_apply  <<<4096, 256, 0, stream>>>(x, partials, gamma, beta, out);
}